// Round 1
// 140.733 us; speedup vs baseline: 1.0134x; 1.0134x over previous
//
#include <hip/hip_runtime.h>

// Problem constants: B=4, C=256, H=W=64, KS=3, N=9
#define HW    4096
#define J_TOT 16384   // B*H*W
#define K_TOT 2304    // 9*256
#define C_CH  256

typedef unsigned short u16;
typedef unsigned int   u32;
typedef __attribute__((ext_vector_type(8))) short short8;   // 8 bf16 (4 VGPRs), MFMA A/B frag
typedef __attribute__((ext_vector_type(4))) float f32x4;    // MFMA C/D frag
typedef __attribute__((ext_vector_type(8))) unsigned short us8;

__device__ __forceinline__ float b2f(u16 u) { return __uint_as_float(((u32)u) << 16); }
__device__ __forceinline__ u16 f2b(float x) {             // RNE f32->bf16
  u32 u = __float_as_uint(x);
  u += 0x7FFFu + ((u >> 16) & 1u);
  return (u16)(u >> 16);
}

// async global->LDS, 16B per lane; lds dst must be wave-uniform base (+lane*16 implicit)
__device__ __forceinline__ void gload_lds16(const u16* g, u16* l) {
  __builtin_amdgcn_global_load_lds(
      (__attribute__((address_space(1))) void*)(void*)g,
      (__attribute__((address_space(3))) void*)(void*)l, 16, 0, 0);
}

// ---------------------------------------------------------------------------
// Kernel 0: dtype detection (1 = bf16 inputs, 0 = f32 inputs).
// ---------------------------------------------------------------------------
__global__ void k_detect(const u16* __restrict__ f, int* __restrict__ flag) {
  __shared__ int sh[256];
  int t = threadIdx.x;
  int hits = 0;
  for (int i = t; i < 2048; i += 256) {
    u16 u = f[2 * i];
    int e = (u >> 7) & 0xFF;
    hits += (e >= 100 && e <= 141) ? 1 : 0;
  }
  sh[t] = hits;
  __syncthreads();
  if (t == 0) {
    int s = 0;
    for (int i = 0; i < 256; i++) s += sh[i];
    flag[0] = (s > 1024) ? 1 : 0;
  }
}

// ---------------------------------------------------------------------------
// Kernel 1: feature (b,c,h,w) -> channels-last bf16 ftr[b][hw][c]
// ---------------------------------------------------------------------------
__global__ void k_transpose(const void* __restrict__ featv, u16* __restrict__ ftr,
                            const int* __restrict__ flag) {
  __shared__ u16 tile[32][33];
  int isbf = *flag;
  int b = blockIdx.z;
  int hw0 = blockIdx.x << 5;
  int c0 = blockIdx.y << 5;
  int tx = threadIdx.x;  // 0..31 (hw on load, c on store)
  int ty = threadIdx.y;  // 0..7
  if (isbf) {
    const u16* f = (const u16*)featv;
#pragma unroll
    for (int i = 0; i < 4; i++) {
      int c = c0 + ty + i * 8;
      tile[ty + i * 8][tx] = f[(((size_t)(b * C_CH + c)) << 12) + hw0 + tx];
    }
  } else {
    const float* f = (const float*)featv;
#pragma unroll
    for (int i = 0; i < 4; i++) {
      int c = c0 + ty + i * 8;
      tile[ty + i * 8][tx] = f2b(f[(((size_t)(b * C_CH + c)) << 12) + hw0 + tx]);
    }
  }
  __syncthreads();
#pragma unroll
  for (int i = 0; i < 4; i++) {
    int hw = hw0 + ty + i * 8;
    ftr[(((size_t)(b * HW + hw)) << 8) + c0 + tx] = tile[tx][ty + i * 8];
  }
}

// ---------------------------------------------------------------------------
// Kernel 2: weight (o,c,3,3) -> Wr[o][k] bf16 with k = n*256 + c, n = i*3+j
// ---------------------------------------------------------------------------
__global__ void k_wconv(const void* __restrict__ wv, u16* __restrict__ Wr,
                        const int* __restrict__ flag) {
  int isbf = *flag;
  int idx = blockIdx.x * 256 + threadIdx.x;      // = o*2304 + n*256 + c
  if (idx >= C_CH * K_TOT) return;
  int c = idx & 255;
  int n = (idx >> 8) % 9;
  int o = idx / K_TOT;
  int src = (o * 256 + c) * 9 + n;
  if (isbf) Wr[idx] = ((const u16*)wv)[src];
  else      Wr[idx] = f2b(((const float*)wv)[src]);
}

// ---------------------------------------------------------------------------
// Kernel 3: bilinear gather -> Xt[j][k] bf16 (j = b*4096+hw, k = n*256+c).
// 16 pixels per block (1024 blocks = 4 blocks/CU). Phase 1: per (pixel,n)
// corner indices + weights. Phase 2: thread (p,cq) handles channels cq*8..+8
// and 128+cq*8..+8 -> each 16-lane group's us8 loads cover a dense 256B
// segment of a bf16 corner row.
// ---------------------------------------------------------------------------
__global__ __launch_bounds__(256) void k_gather(const void* __restrict__ offv,
                                                const u16* __restrict__ ftr,
                                                u16* __restrict__ Xt,
                                                const int* __restrict__ flag) {
  __shared__ float gs[9][4][16];
  __shared__ int   isx[9][4][16];
  int isbf = *flag;
  int j0 = blockIdx.x << 4;
  int b = j0 >> 12;
  int hw0 = j0 & (HW - 1);
  int t = threadIdx.x;

  if (t < 144) {
    int p = t & 15, n = t >> 4;
    int hw = hw0 + p;
    int h = hw >> 6, w = hw & 63;
    size_t obi = (((size_t)(b * 18 + n)) << 12) + hw;
    float ox, oy;
    if (isbf) {
      const u16* po = (const u16*)offv;
      ox = b2f(po[obi]);
      oy = b2f(po[obi + (9u << 12)]);
    } else {
      const float* po = (const float*)offv;
      ox = po[obi];
      oy = po[obi + (9u << 12)];
    }
    int ki = n / 3, kj = n % 3;
    float px = (float)(h + ki) + ox;
    float py = (float)(w + kj) + oy;
    float fx = floorf(px), fy = floorf(py);
    float qltx = fminf(fmaxf(fx, 0.f), 65.f);
    float qlty = fminf(fmaxf(fy, 0.f), 65.f);
    float qrbx = fminf(fmaxf(fx + 1.f, 0.f), 65.f);
    float qrby = fminf(fmaxf(fy + 1.f, 0.f), 65.f);
    float pcx = fminf(fmaxf(px, 0.f), 65.f);
    float pcy = fminf(fmaxf(py, 0.f), 65.f);
    float dltx = 1.f + (qltx - pcx);
    float drbx = 1.f - (qrbx - pcx);
    float dlty = 1.f + (qlty - pcy);
    float drby = 1.f - (qrby - pcy);
    float g0 = dltx * dlty;   // (q_lt_x, q_lt_y)
    float g1 = drbx * drby;   // (q_rb_x, q_rb_y)
    float g2 = dltx * drby;   // (q_lt_x, q_rb_y)
    float g3 = drbx * dlty;   // (q_rb_x, q_lt_y)
    int x0 = (int)qltx, y0 = (int)qlty, x1 = (int)qrbx, y1 = (int)qrby;
    int v0 = (x0 >= 1 && x0 <= 64 && y0 >= 1 && y0 <= 64);
    int v1 = (x1 >= 1 && x1 <= 64 && y1 >= 1 && y1 <= 64);
    int v2 = (x0 >= 1 && x0 <= 64 && y1 >= 1 && y1 <= 64);
    int v3 = (x1 >= 1 && x1 <= 64 && y0 >= 1 && y0 <= 64);
    int base = b << 12;
    isx[n][0][p] = v0 ? ((base + ((x0 - 1) << 6) + (y0 - 1)) << 8) : 0;
    isx[n][1][p] = v1 ? ((base + ((x1 - 1) << 6) + (y1 - 1)) << 8) : 0;
    isx[n][2][p] = v2 ? ((base + ((x0 - 1) << 6) + (y1 - 1)) << 8) : 0;
    isx[n][3][p] = v3 ? ((base + ((x1 - 1) << 6) + (y0 - 1)) << 8) : 0;
    gs[n][0][p] = v0 ? g0 : 0.f;
    gs[n][1][p] = v1 ? g1 : 0.f;
    gs[n][2][p] = v2 ? g2 : 0.f;
    gs[n][3][p] = v3 ? g3 : 0.f;
  }
  __syncthreads();

  int p = t >> 4, cq = t & 15;
  size_t rowb = (size_t)(j0 + p) * K_TOT;
  int cA = cq * 8, cB = 128 + cq * 8;
  for (int n = 0; n < 9; n++) {
    float g0 = gs[n][0][p], g1 = gs[n][1][p], g2 = gs[n][2][p], g3 = gs[n][3][p];
    const u16* f0 = ftr + isx[n][0][p];
    const u16* f1 = ftr + isx[n][1][p];
    const u16* f2 = ftr + isx[n][2][p];
    const u16* f3 = ftr + isx[n][3][p];
    u16* dst = Xt + rowb + n * 256;
#pragma unroll
    for (int half = 0; half < 2; half++) {
      int c = half ? cB : cA;
      us8 r0 = *(const us8*)(f0 + c);
      us8 r1 = *(const us8*)(f1 + c);
      us8 r2 = *(const us8*)(f2 + c);
      us8 r3 = *(const us8*)(f3 + c);
      us8 ov;
#pragma unroll
      for (int i = 0; i < 8; i++) {
        float v = g0 * b2f(r0[i]) + g1 * b2f(r1[i]) + g2 * b2f(r2[i]) + g3 * b2f(r3[i]);
        ov[i] = f2b(v);
      }
      *(us8*)(dst + c) = ov;
    }
  }
}

// ---------------------------------------------------------------------------
// Kernel 4: GEMM  out[o][j] = sum_k Wr[o][k]*Xt[j][k], fused epilogue
// relu(relu(acc) + feature). Tile 128j x 64o, 4 waves (2j x 2o), wave tile
// 64j x 32o (2x4 frags of 16x16x32). Grid (128,4) = 512 blocks = 2 blocks/CU.
//
// Pipeline (T3+T4): BK=64, TRIPLE-buffered LDS (72KB), counted vmcnt(6) --
// each iteration issues the stage for tile t+2 (6 gload_lds16/wave), computes
// tile t (12 ds_read_b128 + 16 MFMA), then waits only for the stage issued a
// FULL ITERATION ago + one raw s_barrier. One barrier per 64 K-elements
// (was 2 per 32). LDS is XOR-swizzled (col8 ^= row&7) via pre-swizzled
// global source (linear gload_lds dest) so fragment ds_read_b128s are <=2-way
// (free per m136).
// ---------------------------------------------------------------------------
#define NT 36   // K_TOT / 64

#define GEMM_STAGE(bufi)                                                     \
  do {                                                                       \
    u16* _bl = &Bs[bufi][wave * 2048];                                       \
    u16* _al = &As[bufi][wave * 1024];                                       \
    gload_lds16(bsrc0, _bl);                                                 \
    gload_lds16(bsrc1, _bl + 512);                                           \
    gload_lds16(bsrc2, _bl + 1024);                                          \
    gload_lds16(bsrc3, _bl + 1536);                                          \
    gload_lds16(asrc0, _al);                                                 \
    gload_lds16(asrc1, _al + 512);                                           \
    bsrc0 += 64; bsrc1 += 64; bsrc2 += 64; bsrc3 += 64;                      \
    asrc0 += 64; asrc1 += 64;                                                \
  } while (0)

#define GEMM_COMPUTE(bufi)                                                   \
  do {                                                                       \
    short8 af[2][2], bf[4][2];                                               \
    _Pragma("unroll")                                                        \
    for (int kk = 0; kk < 2; kk++) {                                         \
      int go = (((kk << 2) + lk) ^ swz) << 3;                                \
      _Pragma("unroll")                                                      \
      for (int oi = 0; oi < 2; oi++)                                         \
        af[oi][kk] = *(const short8*)(As[bufi] + (wo * 32 + oi * 16 + lr) * 64 + go); \
      _Pragma("unroll")                                                      \
      for (int ji = 0; ji < 4; ji++)                                         \
        bf[ji][kk] = *(const short8*)(Bs[bufi] + (wj * 64 + ji * 16 + lr) * 64 + go); \
    }                                                                        \
    __builtin_amdgcn_s_setprio(1);                                           \
    _Pragma("unroll")                                                        \
    for (int kk = 0; kk < 2; kk++)                                           \
      _Pragma("unroll")                                                      \
      for (int oi = 0; oi < 2; oi++)                                         \
        _Pragma("unroll")                                                    \
        for (int ji = 0; ji < 4; ji++)                                       \
          acc[oi][ji] = __builtin_amdgcn_mfma_f32_16x16x32_bf16(             \
              af[oi][kk], bf[ji][kk], acc[oi][ji], 0, 0, 0);                 \
    __builtin_amdgcn_s_setprio(0);                                           \
  } while (0)

__global__ __launch_bounds__(256) void k_gemm(const u16* __restrict__ Wr,
                                              const u16* __restrict__ Xt,
                                              const void* __restrict__ featv,
                                              void* __restrict__ outv,
                                              const int* __restrict__ flag) {
  __shared__ u16 Bs[3][128 * 64];   // [j_row][k] 16KB x3
  __shared__ u16 As[3][64 * 64];    // [o_row][k]  8KB x3
  int isbf = *flag;
  // pin the flag load's completion before staging so in-loop vmcnt counts
  // see exactly the 6 outstanding gload_lds per wave per stage
  asm volatile("" :: "s"(isbf));
  int jb = blockIdx.x << 7;
  int ob0 = blockIdx.y << 6;
  int t = threadIdx.x;
  int wave = t >> 6, lane = t & 63;
  int wj = wave >> 1, wo = wave & 1;
  int lr = lane & 15, lk = lane >> 4;
  int swz = lr & 7;

  f32x4 acc[2][4];   // [oi][ji]
  f32x4 zero = {0.f, 0.f, 0.f, 0.f};
#pragma unroll
  for (int i = 0; i < 2; i++)
#pragma unroll
    for (int j = 0; j < 4; j++) acc[i][j] = zero;

  // staging: each wave stages B rows [32w,32w+32) via 4 instrs (8 rows each)
  // and A rows [16w,16w+16) via 2 instrs. Lane l covers row +(l>>3),
  // col-group l&7; source column pre-swizzled: cg_src = (l&7) ^ (l>>3)
  // so that LDS slot (r, cg) holds global column (cg ^ (r&7)).
  int rb = lane >> 3;                  // 0..7
  int cs = ((lane & 7) ^ rb) << 3;     // pre-swizzled source k-offset (elems)
  const u16* bsrc0 = Xt + (size_t)(jb + wave * 32 +  0 + rb) * K_TOT + cs;
  const u16* bsrc1 = Xt + (size_t)(jb + wave * 32 +  8 + rb) * K_TOT + cs;
  const u16* bsrc2 = Xt + (size_t)(jb + wave * 32 + 16 + rb) * K_TOT + cs;
  const u16* bsrc3 = Xt + (size_t)(jb + wave * 32 + 24 + rb) * K_TOT + cs;
  const u16* asrc0 = Wr + (size_t)(ob0 + wave * 16 + 0 + rb) * K_TOT + cs;
  const u16* asrc1 = Wr + (size_t)(ob0 + wave * 16 + 8 + rb) * K_TOT + cs;

  // prologue: fill buffers 0 and 1; wait for buffer 0 only (12 -> 6 in flight)
  GEMM_STAGE(0);
  GEMM_STAGE(1);
  asm volatile("s_waitcnt vmcnt(6)" ::: "memory");
  __builtin_amdgcn_s_barrier();

  int cb = 0, sb = 2;
  for (int tt = 0; tt < NT - 2; ++tt) {
    GEMM_STAGE(sb);          // tile tt+2 in flight
    GEMM_COMPUTE(cb);        // tile tt
    // wait for tile tt+1's stage (issued last iter); tt+2's 6 stay in flight
    asm volatile("s_waitcnt vmcnt(6)" ::: "memory");
    __builtin_amdgcn_s_barrier();
    cb = (cb + 1 == 3) ? 0 : cb + 1;
    sb = (sb + 1 == 3) ? 0 : sb + 1;
  }
  GEMM_COMPUTE(cb);          // tile NT-2
  asm volatile("s_waitcnt vmcnt(0)" ::: "memory");
  __builtin_amdgcn_s_barrier();
  cb = (cb + 1 == 3) ? 0 : cb + 1;
  GEMM_COMPUTE(cb);          // tile NT-1

  // epilogue: D mapping col = lane&15 (j), row = (lane>>4)*4 + r (o)
  int lq = lane >> 4;
#pragma unroll
  for (int oi = 0; oi < 2; oi++) {
#pragma unroll
    for (int ji = 0; ji < 4; ji++) {
      int j = jb + wj * 64 + ji * 16 + lr;
      int bb_ = j >> 12, hw = j & (HW - 1);
      int o0 = ob0 + wo * 32 + oi * 16 + lq * 4;
#pragma unroll
      for (int r = 0; r < 4; r++) {
        size_t oidx = (((size_t)(bb_ * C_CH + o0 + r)) << 12) + hw;
        float v = acc[oi][ji][r];
        v = fmaxf(v, 0.f);
        float ft = isbf ? b2f(((const u16*)featv)[oidx]) : ((const float*)featv)[oidx];
        v = fmaxf(v + ft, 0.f);
        if (isbf) ((u16*)outv)[oidx] = f2b(v);
        else      ((float*)outv)[oidx] = v;
      }
    }
  }
}

extern "C" void kernel_launch(void* const* d_in, const int* in_sizes, int n_in,
                              void* d_out, int out_size, void* d_ws, size_t ws_size,
                              hipStream_t stream) {
  const void* feat = d_in[0];
  const void* offs = d_in[1];
  const void* wght = d_in[2];

  // workspace layout (256B-aligned sections), total ~85.1 MB
  const size_t off_flag = 0;
  const size_t off_wr   = 256;                          // bf16 Wr, 1.125 MB
  const size_t off_ftr  = off_wr + (size_t)1179648;     // bf16 channels-last feature, 8 MB
  const size_t off_xt   = off_ftr + (size_t)8388608;    // bf16 Xt, 72 MB
  const size_t need     = off_xt + (size_t)75497472;
  if (ws_size < need) return;  // insufficient scratch; cannot run

  char* ws = (char*)d_ws;
  int* flag = (int*)(ws + off_flag);
  u16* Wr   = (u16*)(ws + off_wr);
  u16* ftr  = (u16*)(ws + off_ftr);
  u16* Xt   = (u16*)(ws + off_xt);

  k_detect<<<1, 256, 0, stream>>>((const u16*)feat, flag);
  k_transpose<<<dim3(128, 8, 4), dim3(32, 8), 0, stream>>>(feat, ftr, flag);
  k_wconv<<<K_TOT, 256, 0, stream>>>(wght, Wr, flag);
  k_gather<<<J_TOT / 16, 256, 0, stream>>>(offs, ftr, Xt, flag);
  k_gemm<<<dim3(J_TOT / 128, 4), 256, 0, stream>>>(Wr, Xt, feat, d_out, flag);
}